// Round 6
// baseline (102.225 us; speedup 1.0000x reference)
//
#include <hip/hip_runtime.h>

using u16    = unsigned short;
using f32x4  = __attribute__((ext_vector_type(4))) float;
using bf16x8 = __attribute__((ext_vector_type(8))) __bf16;

#define E_CNT 400000
#define G_CNT 1024
#define NROWS 401024   // E+G = 3133*128 exactly
#define NBLK  3133

// ws layout (bytes)
#define WS_NRBF   0u          // [65536][128] bf16 = 16777216
#define WS_GFBF   16777216u   // [1024][384] bf16  =   786432
#define WS_WTF    17563648u   // [17][8][64] x 16B =   139264  (B frags: chunk c, fn, lane)
#define WS_NME    17702912u   // [160] bf16        =      320
#define WS_BIAS   17703232u   // [128] f32         =      512

__device__ __forceinline__ u16 f2bf(float f) {
  unsigned u = __builtin_bit_cast(unsigned, f);
  return (u16)((u + 0x7fffu + ((u >> 16) & 1u)) >> 16);  // RNE
}

__device__ __forceinline__ void gload16(const void* g, void* l) {
  __builtin_amdgcn_global_load_lds((const __attribute__((address_space(1))) void*)g,
                                   (__attribute__((address_space(3))) void*)l, 16, 0, 0);
}

// ---------- precompute kernels ----------

__global__ __launch_bounds__(256) void k_conv_nr(const float4* __restrict__ in,
                                                 u16* __restrict__ out) {
  int i = blockIdx.x * 256 + threadIdx.x;
  float4 v = in[i];
  unsigned lo = (unsigned)f2bf(v.x) | ((unsigned)f2bf(v.y) << 16);
  unsigned hi = (unsigned)f2bf(v.z) | ((unsigned)f2bf(v.w) << 16);
  reinterpret_cast<uint2*>(out)[i] = make_uint2(lo, hi);
}

__global__ __launch_bounds__(128) void k_gf(const float* __restrict__ imr,
                                            const float* __restrict__ pgr,
                                            const float* __restrict__ nr,
                                            const int* __restrict__ focus,
                                            u16* __restrict__ gfbf) {
  int g = blockIdx.x, t = threadIdx.x;
  int fi = focus[g];
  u16* row = gfbf + (size_t)g * 384;
  row[t]       = f2bf(imr[(size_t)g * 128 + t]);
  row[128 + t] = f2bf(pgr[(size_t)g * 128 + t]);
  row[256 + t] = f2bf(nr[(size_t)fi * 128 + t]);
}

// WTf[c][fn][lane(lr,lg)][j] = W1col[fn*16+lr][c*32+lg*8+j]  (zero-pad k>=516)
__global__ __launch_bounds__(256) void k_wt(const float* __restrict__ sW1,
                                            const float* __restrict__ tW1,
                                            u16* __restrict__ wtf) {
  int idx = blockIdx.x * 256 + threadIdx.x;
  if (idx >= 17 * 8 * 64 * 8) return;
  int j = idx & 7, l = (idx >> 3) & 63, fn = (idx >> 9) & 7, c = idx >> 12;
  int lr = l & 15, lg = l >> 4;
  int col = fn * 16 + lr;
  int k = c * 32 + lg * 8 + j;
  float v = 0.f;
  if (k < 516) v = (col < 64) ? sW1[(size_t)k * 64 + col] : tW1[(size_t)k * 64 + (col - 64)];
  wtf[idx] = f2bf(v);
}

__global__ __launch_bounds__(256) void k_misc(const float* __restrict__ nme,
                                              const float* __restrict__ sb1,
                                              const float* __restrict__ tb1,
                                              u16* __restrict__ nmebf,
                                              float* __restrict__ bias) {
  int t = threadIdx.x;
  if (t < 160) nmebf[t] = (t < 132) ? f2bf(nme[t]) : (u16)0;
  if (t < 64) bias[t] = sb1[t];
  else if (t < 128) bias[t] = tb1[t - 64];
}

// ---------- barrier-free gather-GEMM: private per-wave DMA rings ----------
// 2 waves/block, each wave fully independent: own 64 rows x 128 cols (acc 4x8),
// own private LDS ring-3 (3 x 4KB). A staged by global_load_lds 3 steps ahead;
// B loaded to regs from L2-hot WTf, double-buffered, prefetch distance 1.
// No s_barrier anywhere. Per-step sync (all intra-wave, counted):
//   vmcnt(4): S(c) [3 steps old] and B(c) [1 step old] complete; S(c+2) may fly
//   lgkmcnt(0)+sched_barrier: own ds_reads done before MFMA (rule 18) and
//   before S(c+3) DMA overwrites the slot being read (ring reuse = 3).
__global__ __launch_bounds__(128, 2) void fused_mlp(
    const u16* __restrict__ NRbf, const u16* __restrict__ GFbf,
    const u16* __restrict__ WTf, const u16* __restrict__ NMEbf,
    const float* __restrict__ bias128,
    const int* __restrict__ tgt, const int* __restrict__ n2g,
    const float* __restrict__ feats, const float* __restrict__ dtab,
    const float* __restrict__ sW2, const float* __restrict__ sb2,
    const float* __restrict__ tW2, const float* __restrict__ tb2,
    float* __restrict__ out0, float* __restrict__ out1) {
  __shared__ uint4 ldsbuf[1536];  // 2 waves x ring-3 x 4KB = 24576 B
  char* const lds = (char*)ldsbuf;

  const int tid = threadIdx.x;
  const int l = tid & 63, w = tid >> 6;
  const int lr = l & 15, lg = l >> 4;
  const int row0w = blockIdx.x * 128 + w * 64;   // wave's first row
  const bool edge = (row0w < E_CNT);             // waves homogeneous (400000%64==0)
  char* const ring = lds + w * 12288;            // private: no inter-wave sharing

  // staging: issue j covers own rows j*16..j*16+15; lane: row rr=l>>2,
  // dest slot l&3 (linear), SOURCE slot (l&3)^q with q=(row>>1)&3=(l>>3)&3
  const int rr = l >> 2;
  const int so = (((l & 3) ^ ((l >> 3) & 3)) << 4);
  const char *pGFs[4], *pNRs[4];
#pragma unroll
  for (int j = 0; j < 4; ++j) {
    int m = row0w + j * 16 + rr;
    if (edge) {
      int t = tgt[m];
      int g = n2g[t];
      pGFs[j] = (const char*)GFbf + (size_t)g * 768 + so;
      pNRs[j] = (const char*)NRbf + (size_t)t * 256 + so;
    } else {
      pGFs[j] = (const char*)GFbf + (size_t)(m - E_CNT) * 768 + so;
      pNRs[j] = (const char*)NMEbf + so;  // zero-padded to 320B
    }
  }
  const char* pWB = (const char*)WTf + l * 16;

  auto stageA = [&](int c2) {
    char* dst = ring + (c2 % 3) * 4096;
#pragma unroll
    for (int j = 0; j < 4; ++j) {
      const char* src = (c2 < 12) ? pGFs[j] + c2 * 64 : pNRs[j] + (c2 - 12) * 64;
      gload16(src, dst + j * 1024);
    }
  };

  const int rdsw = ((lg ^ ((lr >> 1) & 3)) << 4);  // read-side swizzled slot

  f32x4 acc[4][8];
#pragma unroll
  for (int i = 0; i < 4; ++i)
#pragma unroll
    for (int j = 0; j < 8; ++j) acc[i][j] = (f32x4){0.f, 0.f, 0.f, 0.f};

  bf16x8 bbuf[2][8];

  // prologue: S0, B0, S1, S2  (order matters for the counted vmcnt)
  stageA(0);
  asm volatile("" ::: "memory");
#pragma unroll
  for (int fn = 0; fn < 8; ++fn)
    bbuf[0][fn] = *(const bf16x8*)(pWB + fn * 1024);
  asm volatile("" ::: "memory");
  stageA(1);
  stageA(2);
  asm volatile("" ::: "memory");

#pragma unroll
  for (int c = 0; c < 16; ++c) {
    // drain S(c) and B(c); steady-state leaves S(c+2) (4 loads) in flight
    if (c == 0)       asm volatile("s_waitcnt vmcnt(8)" ::: "memory");
    else if (c <= 13) asm volatile("s_waitcnt vmcnt(4)" ::: "memory");
    else              asm volatile("s_waitcnt vmcnt(0)" ::: "memory");

    // own A-frags for this step
    bf16x8 aF[4];
#pragma unroll
    for (int fm = 0; fm < 4; ++fm)
      aF[fm] = *(const bf16x8*)(ring + (c % 3) * 4096 + (fm * 16 + lr) * 64 + rdsw);

    // B prefetch distance 1 (true double buffer: writes bbuf[(c+1)&1])
    if (c <= 15) {
#pragma unroll
      for (int fn = 0; fn < 8; ++fn)
        bbuf[(c + 1) & 1][fn] = *(const bf16x8*)(pWB + ((c + 1) * 8 + fn) * 1024);
    }

    // own ds_reads drained before MFMA consumes them (rule 18) and before
    // S(c+3) DMA overwrites slot (c+3)%3 == c%3
    asm volatile("s_waitcnt lgkmcnt(0)" ::: "memory");
    __builtin_amdgcn_sched_barrier(0);
    if (c <= 12) stageA(c + 3);
    asm volatile("" ::: "memory");

#pragma unroll
    for (int fm = 0; fm < 4; ++fm)
#pragma unroll
      for (int fn = 0; fn < 8; ++fn)
        acc[fm][fn] = __builtin_amdgcn_mfma_f32_16x16x32_bf16(aF[fm], bbuf[c & 1][fn], acc[fm][fn], 0, 0, 0);
  }

  // ---- tail chunk c=16 (k 512..543): A built in registers, B16 in bbuf[0]
  asm volatile("s_waitcnt vmcnt(0)" ::: "memory");
#pragma unroll
  for (int fm = 0; fm < 4; ++fm) {
    union { u16 u[8]; bf16x8 v; } tt;
#pragma unroll
    for (int j = 0; j < 8; ++j) tt.u[j] = 0;
    if (lg == 0) {  // k=512..519: [dist_emb, f1, f2, f3, 0,0,0,0]
      if (edge) {
        const float4 f = *(const float4*)(feats + (size_t)(row0w + fm * 16 + lr) * 4);
        int td = (int)fminf(f.x, 9.0f);
        tt.u[0] = f2bf(dtab[td]); tt.u[1] = f2bf(f.y);
        tt.u[2] = f2bf(f.z);      tt.u[3] = f2bf(f.w);
      } else {
        tt.u[0] = NMEbf[128]; tt.u[1] = NMEbf[129];
        tt.u[2] = NMEbf[130]; tt.u[3] = NMEbf[131];
      }
    }
#pragma unroll
    for (int fn = 0; fn < 8; ++fn)
      acc[fm][fn] = __builtin_amdgcn_mfma_f32_16x16x32_bf16(tt.v, bbuf[0][fn], acc[fm][fn], 0, 0, 0);
  }

  // ---- epilogues. C layout: col = fn*16+lr, row = fm*16 + lg*4 + rg ----
  {  // scorer head: hidden cols 0..63 = fn 0..3
    float w2v[4], bb[4];
#pragma unroll
    for (int fn = 0; fn < 4; ++fn) {
      int hh = fn * 16 + lr;
      w2v[fn] = sW2[hh];
      bb[fn] = bias128[hh];
    }
    float b2 = sb2[0];
#pragma unroll
    for (int fm = 0; fm < 4; ++fm) {
      float p[4] = {0.f, 0.f, 0.f, 0.f};
#pragma unroll
      for (int fn = 0; fn < 4; ++fn)
#pragma unroll
        for (int rg = 0; rg < 4; ++rg)
          p[rg] += fmaxf(acc[fm][fn][rg] + bb[fn], 0.f) * w2v[fn];
#pragma unroll
      for (int rg = 0; rg < 4; ++rg)
#pragma unroll
        for (int m = 1; m < 16; m <<= 1) p[rg] += __shfl_xor(p[rg], m, 64);
      if (lr == 0) {
        int rbase = row0w + fm * 16 + lg * 4;
        *(float4*)(out0 + rbase) = make_float4(p[0] + b2, p[1] + b2, p[2] + b2, p[3] + b2);
      }
    }
  }
  if (edge) {  // type head: hidden cols 64..127 = fn 4..7
    float bb[4], tw0[4], tw1[4], tw2v[4];
#pragma unroll
    for (int fn = 0; fn < 4; ++fn) {
      int hh = fn * 16 + lr;
      bb[fn] = bias128[64 + hh];
      tw0[fn] = tW2[hh * 3 + 0];
      tw1[fn] = tW2[hh * 3 + 1];
      tw2v[fn] = tW2[hh * 3 + 2];
    }
    float tb0 = tb2[0], tb1 = tb2[1], tb2s = tb2[2];
#pragma unroll
    for (int fm = 0; fm < 4; ++fm) {
      float p0[4] = {0.f, 0.f, 0.f, 0.f}, p1[4] = {0.f, 0.f, 0.f, 0.f}, p2[4] = {0.f, 0.f, 0.f, 0.f};
#pragma unroll
      for (int fn = 0; fn < 4; ++fn)
#pragma unroll
        for (int rg = 0; rg < 4; ++rg) {
          float h = fmaxf(acc[fm][fn + 4][rg] + bb[fn], 0.f);
          p0[rg] += h * tw0[fn];
          p1[rg] += h * tw1[fn];
          p2[rg] += h * tw2v[fn];
        }
#pragma unroll
      for (int rg = 0; rg < 4; ++rg)
#pragma unroll
        for (int m = 1; m < 16; m <<= 1) {
          p0[rg] += __shfl_xor(p0[rg], m, 64);
          p1[rg] += __shfl_xor(p1[rg], m, 64);
          p2[rg] += __shfl_xor(p2[rg], m, 64);
        }
      if (lr == 0) {
        int rbase = row0w + fm * 16 + lg * 4;
        float* dst = out1 + (size_t)rbase * 3;  // 12 consecutive f32, 16B-aligned
        *(float4*)(dst + 0) = make_float4(p0[0] + tb0, p1[0] + tb1, p2[0] + tb2s, p0[1] + tb0);
        *(float4*)(dst + 4) = make_float4(p1[1] + tb1, p2[1] + tb2s, p0[2] + tb0, p1[2] + tb1);
        *(float4*)(dst + 8) = make_float4(p2[2] + tb2s, p0[3] + tb0, p1[3] + tb1, p2[3] + tb2s);
      }
    }
  }
}

extern "C" void kernel_launch(void* const* d_in, const int* in_sizes, int n_in,
                              void* d_out, int out_size, void* d_ws, size_t ws_size,
                              hipStream_t stream) {
  const float* imr   = (const float*)d_in[0];
  const float* pgr   = (const float*)d_in[1];
  const float* nr    = (const float*)d_in[2];
  const int*   focus = (const int*)d_in[3];
  const int*   n2g   = (const int*)d_in[4];
  const int*   tgt   = (const int*)d_in[5];
  const float* feats = (const float*)d_in[6];
  const float* dtab  = (const float*)d_in[8];
  const float* nme   = (const float*)d_in[9];
  const float* sW1   = (const float*)d_in[10];
  const float* sb1   = (const float*)d_in[11];
  const float* sW2   = (const float*)d_in[12];
  const float* sb2   = (const float*)d_in[13];
  const float* tW1   = (const float*)d_in[14];
  const float* tb1   = (const float*)d_in[15];
  const float* tW2   = (const float*)d_in[16];
  const float* tb2   = (const float*)d_in[17];

  char* ws = (char*)d_ws;
  u16*   NRbf  = (u16*)(ws + WS_NRBF);
  u16*   GFbf  = (u16*)(ws + WS_GFBF);
  u16*   WTf   = (u16*)(ws + WS_WTF);
  u16*   NMEbf = (u16*)(ws + WS_NME);
  float* bias  = (float*)(ws + WS_BIAS);

  float* out0 = (float*)d_out;          // [401024]
  float* out1 = out0 + NROWS;           // [400000*3]

  k_conv_nr<<<8192, 256, 0, stream>>>((const float4*)nr, NRbf);
  k_gf<<<1024, 128, 0, stream>>>(imr, pgr, nr, focus, GFbf);
  k_wt<<<272, 256, 0, stream>>>(sW1, tW1, WTf);
  k_misc<<<1, 256, 0, stream>>>(nme, sb1, tb1, NMEbf, bias);
  fused_mlp<<<NBLK, 128, 0, stream>>>(NRbf, GFbf, WTf, NMEbf, bias, tgt, n2g, feats,
                                      dtab, sW2, sb2, tW2, tb2, out0, out1);
}

// Round 7
// 89.338 us; speedup vs baseline: 1.1442x; 1.1442x over previous
//
#include <hip/hip_runtime.h>

using u16    = unsigned short;
using f32x4  = __attribute__((ext_vector_type(4))) float;
using bf16x8 = __attribute__((ext_vector_type(8))) __bf16;

#define E_CNT 400000
#define G_CNT 1024

// ws layout (bytes)
#define WS_HNR   0u          // [65536][128] bf16 (permuted cols) = 16777216
#define WS_HGF   16777216u   // [1024][128] f32  (permuted, +b1)  =   524288
#define WS_WFRAG 17301504u   // [16][8][64] x 16B bf16 W1c frags  =   131072
#define WS_D10   17432576u   // [10][128] f32 (permuted)          =     5120
#define WS_CT    17437696u   // [7][128] f32 (permuted)           =     3584
#define WS_NMEH  17441280u   // [128] f32 (permuted)              =      512

__device__ __forceinline__ u16 f2bf(float f) {
  unsigned u = __builtin_bit_cast(unsigned, f);
  return (u16)((u + 0x7fffu + ((u >> 16) & 1u)) >> 16);  // RNE
}
__device__ __forceinline__ float b2f(u16 v) {
  unsigned u = ((unsigned)v) << 16;
  return __builtin_bit_cast(float, u);
}
__device__ __forceinline__ uint4 pack8(f32x4 a, f32x4 b) {
  uint4 r;
  r.x = (unsigned)f2bf(a[0]) | ((unsigned)f2bf(a[1]) << 16);
  r.y = (unsigned)f2bf(a[2]) | ((unsigned)f2bf(a[3]) << 16);
  r.z = (unsigned)f2bf(b[0]) | ((unsigned)f2bf(b[1]) << 16);
  r.w = (unsigned)f2bf(b[2]) | ((unsigned)f2bf(b[3]) << 16);
  return r;
}
// combined first-layer weight: col j<64 -> scorer_W1[:,j], else type_W1[:,j-64]
__device__ __forceinline__ float w1c(const float* sW1, const float* tW1, int k, int j) {
  return (j < 64) ? sW1[(size_t)k * 64 + j] : tW1[(size_t)k * 64 + (j - 64)];
}

// ---------- precompute kernels ----------

// WFRAG[c][fn][lane(lr,lg)][j8] = W1c[k = c*32+lg*8+j][col = fn*16+lr], c<16 (k<512)
__global__ __launch_bounds__(256) void k_wfrag(const float* __restrict__ sW1,
                                               const float* __restrict__ tW1,
                                               u16* __restrict__ wfrag) {
  int idx = blockIdx.x * 256 + threadIdx.x;  // 65536 total
  int j = idx & 7, l = (idx >> 3) & 63, fn = (idx >> 9) & 7, c = idx >> 12;
  int col = fn * 16 + (l & 15);
  int k = c * 32 + (l >> 4) * 8 + j;
  wfrag[idx] = f2bf(w1c(sW1, tW1, k, col));
}

// permuted small tables: position p = q*8+i holds column j = i*16+q
// CT rows: 0..2 = W1c[513..515]; 3 = sW2 (i<4 half); 4..6 = tW2 cols (i>=4 half)
__global__ __launch_bounds__(256) void k_misc2(const float* __restrict__ nme,
                                               const float* __restrict__ sW1,
                                               const float* __restrict__ tW1,
                                               const float* __restrict__ sW2,
                                               const float* __restrict__ tW2,
                                               const float* __restrict__ dtab,
                                               float* __restrict__ d10,
                                               float* __restrict__ ct,
                                               float* __restrict__ nmeh) {
  int p = threadIdx.x;
  if (p >= 128) return;
  int q = p >> 3, i = p & 7, j = i * 16 + q;
  ct[0 * 128 + p] = w1c(sW1, tW1, 513, j);
  ct[1 * 128 + p] = w1c(sW1, tW1, 514, j);
  ct[2 * 128 + p] = w1c(sW1, tW1, 515, j);
  ct[3 * 128 + p] = (i < 4) ? sW2[j] : 0.f;
  if (i >= 4) {
    int jj = j - 64;
    ct[4 * 128 + p] = tW2[jj * 3 + 0];
    ct[5 * 128 + p] = tW2[jj * 3 + 1];
    ct[6 * 128 + p] = tW2[jj * 3 + 2];
  } else {
    ct[4 * 128 + p] = 0.f; ct[5 * 128 + p] = 0.f; ct[6 * 128 + p] = 0.f;
  }
  float s = 0.f;
  for (int k = 0; k < 132; ++k) s += nme[k] * w1c(sW1, tW1, 384 + k, j);
  nmeh[p] = s;
  float w512 = w1c(sW1, tW1, 512, j);
  for (int d = 0; d < 10; ++d) d10[d * 128 + p] = dtab[d] * w512;
}

// H_nr[65536][128] bf16 = NR_f32 x W1c[384:512]; stored permuted:
// lane lr writes its 8 fn-values contiguously at [m][lr*8..+8)
__global__ __launch_bounds__(128) void k_hnr(const float* __restrict__ nr,
                                             const u16* __restrict__ wfrag,
                                             u16* __restrict__ hnr) {
  int tid = threadIdx.x;
  int w = tid >> 6, l = tid & 63, lr = l & 15, lg = l >> 4;
  int row0 = blockIdx.x * 128 + w * 64;
  f32x4 acc[4][8];
#pragma unroll
  for (int i = 0; i < 4; ++i)
#pragma unroll
    for (int j = 0; j < 8; ++j) acc[i][j] = (f32x4){0.f, 0.f, 0.f, 0.f};
#pragma unroll
  for (int c2 = 0; c2 < 4; ++c2) {
    bf16x8 aF[4], bF[8];
#pragma unroll
    for (int fm = 0; fm < 4; ++fm) {
      const float* ap = nr + (size_t)(row0 + fm * 16 + lr) * 128 + c2 * 32 + lg * 8;
      aF[fm] = __builtin_bit_cast(bf16x8, pack8(*(const f32x4*)ap, *(const f32x4*)(ap + 4)));
    }
#pragma unroll
    for (int fn = 0; fn < 8; ++fn)
      bF[fn] = *(const bf16x8*)((const char*)wfrag + (size_t)((12 + c2) * 8 + fn) * 1024 + l * 16);
#pragma unroll
    for (int fm = 0; fm < 4; ++fm)
#pragma unroll
      for (int fn = 0; fn < 8; ++fn)
        acc[fm][fn] = __builtin_amdgcn_mfma_f32_16x16x32_bf16(aF[fm], bF[fn], acc[fm][fn], 0, 0, 0);
  }
#pragma unroll
  for (int fm = 0; fm < 4; ++fm)
#pragma unroll
    for (int rg = 0; rg < 4; ++rg) {
      int m = row0 + fm * 16 + lg * 4 + rg;
      uint4 pk;
      pk.x = (unsigned)f2bf(acc[fm][0][rg]) | ((unsigned)f2bf(acc[fm][1][rg]) << 16);
      pk.y = (unsigned)f2bf(acc[fm][2][rg]) | ((unsigned)f2bf(acc[fm][3][rg]) << 16);
      pk.z = (unsigned)f2bf(acc[fm][4][rg]) | ((unsigned)f2bf(acc[fm][5][rg]) << 16);
      pk.w = (unsigned)f2bf(acc[fm][6][rg]) | ((unsigned)f2bf(acc[fm][7][rg]) << 16);
      *(uint4*)(hnr + (size_t)m * 128 + lr * 8) = pk;
    }
}

// H_gf[1024][128] f32 = [imr|pgr|nr[focus]] x W1c[0:384] + b1c; permuted store
__global__ __launch_bounds__(64) void k_hgf(const float* __restrict__ imr,
                                            const float* __restrict__ pgr,
                                            const float* __restrict__ nr,
                                            const int* __restrict__ focus,
                                            const u16* __restrict__ wfrag,
                                            const float* __restrict__ sb1,
                                            const float* __restrict__ tb1,
                                            float* __restrict__ hgf) {
  int l = threadIdx.x, lr = l & 15, lg = l >> 4;
  int row0 = blockIdx.x * 64;
  int fo[4];
#pragma unroll
  for (int fm = 0; fm < 4; ++fm) fo[fm] = focus[row0 + fm * 16 + lr];
  f32x4 acc[4][8];
#pragma unroll
  for (int i = 0; i < 4; ++i)
#pragma unroll
    for (int j = 0; j < 8; ++j) acc[i][j] = (f32x4){0.f, 0.f, 0.f, 0.f};
#pragma unroll
  for (int c2 = 0; c2 < 12; ++c2) {
    bf16x8 aF[4], bF[8];
#pragma unroll
    for (int fm = 0; fm < 4; ++fm) {
      const float* ap;
      if (c2 < 4)      ap = imr + (size_t)(row0 + fm * 16 + lr) * 128 + c2 * 32;
      else if (c2 < 8) ap = pgr + (size_t)(row0 + fm * 16 + lr) * 128 + (c2 - 4) * 32;
      else             ap = nr + (size_t)fo[fm] * 128 + (c2 - 8) * 32;
      ap += lg * 8;
      aF[fm] = __builtin_bit_cast(bf16x8, pack8(*(const f32x4*)ap, *(const f32x4*)(ap + 4)));
    }
#pragma unroll
    for (int fn = 0; fn < 8; ++fn)
      bF[fn] = *(const bf16x8*)((const char*)wfrag + (size_t)(c2 * 8 + fn) * 1024 + l * 16);
#pragma unroll
    for (int fm = 0; fm < 4; ++fm)
#pragma unroll
      for (int fn = 0; fn < 8; ++fn)
        acc[fm][fn] = __builtin_amdgcn_mfma_f32_16x16x32_bf16(aF[fm], bF[fn], acc[fm][fn], 0, 0, 0);
  }
#pragma unroll
  for (int fm = 0; fm < 4; ++fm)
#pragma unroll
    for (int rg = 0; rg < 4; ++rg) {
      int g = row0 + fm * 16 + lg * 4 + rg;
      f32x4 v0, v1;
#pragma unroll
      for (int fn = 0; fn < 4; ++fn) v0[fn] = acc[fm][fn][rg] + sb1[fn * 16 + lr];
#pragma unroll
      for (int fn = 0; fn < 4; ++fn) v1[fn] = acc[fm][fn + 4][rg] + tb1[fn * 16 + lr];
      *(f32x4*)(hgf + (size_t)g * 128 + lr * 8) = v0;
      *(f32x4*)(hgf + (size_t)g * 128 + lr * 8 + 4) = v1;
    }
}

// stop rows: out0[E+g] = sW2 . relu(Hgf[g] + nmeH) + sb2
__global__ __launch_bounds__(256) void k_stop(const float* __restrict__ hgf,
                                              const float* __restrict__ nmeh,
                                              const float* __restrict__ ct,
                                              const float* __restrict__ sb2,
                                              float* __restrict__ out0) {
  int tid = threadIdx.x;
  int q = tid & 15;
  int gg = blockIdx.x * 16 + (tid >> 4);
  f32x4 hg0 = *(const f32x4*)(hgf + (size_t)gg * 128 + q * 8);
  f32x4 nm0 = *(const f32x4*)(nmeh + q * 8);
  f32x4 w2v = *(const f32x4*)(ct + 3 * 128 + q * 8);
  float sc = 0.f;
#pragma unroll
  for (int i = 0; i < 4; ++i) sc += fmaxf(hg0[i] + nm0[i], 0.f) * w2v[i];
#pragma unroll
  for (int m = 1; m < 16; m <<= 1) sc += __shfl_xor(sc, m, 64);
  if (q == 0) out0[E_CNT + gg] = sc + sb2[0];
}

// ---------- hot kernel: per-edge gather + elementwise + dual head ----------
// 16 lanes/edge, lane q owns permuted units p=q*8..q*8+7 (cols j=i*16+q:
// i<4 -> scorer cols, i>=4 -> type cols). 2 edges per 16-lane slice,
// pipelined. No LDS, no barriers.
__global__ __launch_bounds__(256) void k_edge(
    const u16* __restrict__ hnr, const float* __restrict__ hgf,
    const float* __restrict__ d10, const float* __restrict__ ct,
    const int* __restrict__ tgt, const int* __restrict__ n2g,
    const float4* __restrict__ feats, const float* __restrict__ sb2,
    const float* __restrict__ tb2, float* __restrict__ out0,
    float* __restrict__ out1) {
  int tid = threadIdx.x;
  int q = tid & 15;
  int eA = blockIdx.x * 32 + (tid >> 4);
  int eB = eA + 16;

  // per-lane weights (loaded once)
  f32x4 wf1a = *(const f32x4*)(ct + 0 * 128 + q * 8), wf1b = *(const f32x4*)(ct + 0 * 128 + q * 8 + 4);
  f32x4 wf2a = *(const f32x4*)(ct + 1 * 128 + q * 8), wf2b = *(const f32x4*)(ct + 1 * 128 + q * 8 + 4);
  f32x4 wf3a = *(const f32x4*)(ct + 2 * 128 + q * 8), wf3b = *(const f32x4*)(ct + 2 * 128 + q * 8 + 4);
  f32x4 w2v  = *(const f32x4*)(ct + 3 * 128 + q * 8);
  f32x4 tw0v = *(const f32x4*)(ct + 4 * 128 + q * 8 + 4);
  f32x4 tw1v = *(const f32x4*)(ct + 5 * 128 + q * 8 + 4);
  f32x4 tw2v = *(const f32x4*)(ct + 6 * 128 + q * 8 + 4);
  float sb2v = sb2[0], tb0 = tb2[0], tb1 = tb2[1], tb2s = tb2[2];

  // index chains for both groups first (overlap latency)
  int tA = tgt[eA], tB = tgt[eB];
  int gA = n2g[tA], gB = n2g[tB];
  float4 fA = feats[eA], fB = feats[eB];
  union { uint4 v; u16 s[8]; } hnA, hnB;
  hnA.v = *(const uint4*)(hnr + (size_t)tA * 128 + q * 8);
  hnB.v = *(const uint4*)(hnr + (size_t)tB * 128 + q * 8);
  f32x4 hgA0 = *(const f32x4*)(hgf + (size_t)gA * 128 + q * 8);
  f32x4 hgA1 = *(const f32x4*)(hgf + (size_t)gA * 128 + q * 8 + 4);
  f32x4 hgB0 = *(const f32x4*)(hgf + (size_t)gB * 128 + q * 8);
  f32x4 hgB1 = *(const f32x4*)(hgf + (size_t)gB * 128 + q * 8 + 4);
  int dA = (int)fminf(fA.x, 9.f), dB = (int)fminf(fB.x, 9.f);
  f32x4 dA0 = *(const f32x4*)(d10 + dA * 128 + q * 8);
  f32x4 dA1 = *(const f32x4*)(d10 + dA * 128 + q * 8 + 4);
  f32x4 dB0 = *(const f32x4*)(d10 + dB * 128 + q * 8);
  f32x4 dB1 = *(const f32x4*)(d10 + dB * 128 + q * 8 + 4);

  // ---- group A ----
  float scA = 0.f, t0A = 0.f, t1A = 0.f, t2A = 0.f;
#pragma unroll
  for (int i = 0; i < 4; ++i) {
    float h = hgA0[i] + b2f(hnA.s[i]) + dA0[i] + fA.y * wf1a[i] + fA.z * wf2a[i] + fA.w * wf3a[i];
    scA += fmaxf(h, 0.f) * w2v[i];
  }
#pragma unroll
  for (int i = 0; i < 4; ++i) {
    float h = hgA1[i] + b2f(hnA.s[4 + i]) + dA1[i] + fA.y * wf1b[i] + fA.z * wf2b[i] + fA.w * wf3b[i];
    float r = fmaxf(h, 0.f);
    t0A += r * tw0v[i]; t1A += r * tw1v[i]; t2A += r * tw2v[i];
  }
  // ---- group B ----
  float scB = 0.f, t0B = 0.f, t1B = 0.f, t2B = 0.f;
#pragma unroll
  for (int i = 0; i < 4; ++i) {
    float h = hgB0[i] + b2f(hnB.s[i]) + dB0[i] + fB.y * wf1a[i] + fB.z * wf2a[i] + fB.w * wf3a[i];
    scB += fmaxf(h, 0.f) * w2v[i];
  }
#pragma unroll
  for (int i = 0; i < 4; ++i) {
    float h = hgB1[i] + b2f(hnB.s[4 + i]) + dB1[i] + fB.y * wf1b[i] + fB.z * wf2b[i] + fB.w * wf3b[i];
    float r = fmaxf(h, 0.f);
    t0B += r * tw0v[i]; t1B += r * tw1v[i]; t2B += r * tw2v[i];
  }

  // ---- 16-lane reductions ----
#pragma unroll
  for (int m = 1; m < 16; m <<= 1) {
    scA += __shfl_xor(scA, m, 64); t0A += __shfl_xor(t0A, m, 64);
    t1A += __shfl_xor(t1A, m, 64); t2A += __shfl_xor(t2A, m, 64);
    scB += __shfl_xor(scB, m, 64); t0B += __shfl_xor(t0B, m, 64);
    t1B += __shfl_xor(t1B, m, 64); t2B += __shfl_xor(t2B, m, 64);
  }
  if (q == 0) {
    out0[eA] = scA + sb2v;
    out0[eB] = scB + sb2v;
    float* oA = out1 + (size_t)eA * 3;
    oA[0] = t0A + tb0; oA[1] = t1A + tb1; oA[2] = t2A + tb2s;
    float* oB = out1 + (size_t)eB * 3;
    oB[0] = t0B + tb0; oB[1] = t1B + tb1; oB[2] = t2B + tb2s;
  }
}

extern "C" void kernel_launch(void* const* d_in, const int* in_sizes, int n_in,
                              void* d_out, int out_size, void* d_ws, size_t ws_size,
                              hipStream_t stream) {
  const float* imr   = (const float*)d_in[0];
  const float* pgr   = (const float*)d_in[1];
  const float* nr    = (const float*)d_in[2];
  const int*   focus = (const int*)d_in[3];
  const int*   n2g   = (const int*)d_in[4];
  const int*   tgt   = (const int*)d_in[5];
  const float* feats = (const float*)d_in[6];
  const float* dtab  = (const float*)d_in[8];
  const float* nme   = (const float*)d_in[9];
  const float* sW1   = (const float*)d_in[10];
  const float* sb1   = (const float*)d_in[11];
  const float* sW2   = (const float*)d_in[12];
  const float* sb2   = (const float*)d_in[13];
  const float* tW1   = (const float*)d_in[14];
  const float* tb1   = (const float*)d_in[15];
  const float* tW2   = (const float*)d_in[16];
  const float* tb2   = (const float*)d_in[17];

  char* ws = (char*)d_ws;
  u16*   HNR   = (u16*)(ws + WS_HNR);
  float* HGF   = (float*)(ws + WS_HGF);
  u16*   WFRAG = (u16*)(ws + WS_WFRAG);
  float* D10   = (float*)(ws + WS_D10);
  float* CT    = (float*)(ws + WS_CT);
  float* NMEH  = (float*)(ws + WS_NMEH);

  float* out0 = (float*)d_out;            // [401024]
  float* out1 = out0 + (E_CNT + G_CNT);   // [400000*3]

  k_wfrag<<<256, 256, 0, stream>>>(sW1, tW1, WFRAG);
  k_misc2<<<1, 256, 0, stream>>>(nme, sW1, tW1, sW2, tW2, dtab, D10, CT, NMEH);
  k_hnr<<<512, 128, 0, stream>>>(nr, WFRAG, HNR);
  k_hgf<<<16, 64, 0, stream>>>(imr, pgr, nr, focus, WFRAG, sb1, tb1, HGF);
  k_stop<<<64, 256, 0, stream>>>(HGF, NMEH, CT, sb2, out0);
  k_edge<<<12500, 256, 0, stream>>>(HNR, HGF, D10, CT, tgt, n2g,
                                    (const float4*)feats, sb2, tb2, out0, out1);
}

// Round 8
// 66.076 us; speedup vs baseline: 1.5471x; 1.3521x over previous
//
#include <hip/hip_runtime.h>

using u16    = unsigned short;
using f32x4  = __attribute__((ext_vector_type(4))) float;
using bf16x8 = __attribute__((ext_vector_type(8))) __bf16;

#define E_CNT 400000
#define G_CNT 1024

// ws layout (bytes)
#define WS_HNR   0u          // [65536][128] bf16 (permuted cols) = 16777216
#define WS_HGF   16777216u   // [1024][128] f32  (permuted, +b1)  =   524288
#define WS_WFRAG 17301504u   // [16][8][64] x 16B bf16 W1c frags  =   131072
#define WS_CT    17432576u   // [8][128] f32 (permuted)           =     4096
#define WS_NMEH  17436672u   // [128] f32 (permuted)              =      512

__device__ __forceinline__ u16 f2bf(float f) {
  unsigned u = __builtin_bit_cast(unsigned, f);
  return (u16)((u + 0x7fffu + ((u >> 16) & 1u)) >> 16);  // RNE
}
__device__ __forceinline__ float b2f(u16 v) {
  unsigned u = ((unsigned)v) << 16;
  return __builtin_bit_cast(float, u);
}
__device__ __forceinline__ uint4 pack8(f32x4 a, f32x4 b) {
  uint4 r;
  r.x = (unsigned)f2bf(a[0]) | ((unsigned)f2bf(a[1]) << 16);
  r.y = (unsigned)f2bf(a[2]) | ((unsigned)f2bf(a[3]) << 16);
  r.z = (unsigned)f2bf(b[0]) | ((unsigned)f2bf(b[1]) << 16);
  r.w = (unsigned)f2bf(b[2]) | ((unsigned)f2bf(b[3]) << 16);
  return r;
}
// combined first-layer weight: col j<64 -> scorer_W1[:,j], else type_W1[:,j-64]
__device__ __forceinline__ float w1c(const float* sW1, const float* tW1, int k, int j) {
  return (j < 64) ? sW1[(size_t)k * 64 + j] : tW1[(size_t)k * 64 + (j - 64)];
}

// ---------- precompute: WFRAG + permuted small tables (fused) ----------
// blocks 0..255: WFRAG[c][fn][lane(lr,lg)][j8] = W1c[c*32+lg*8+j][fn*16+(l&15)]
// block 256: CT rows (permuted p=q*8+i <-> col j=i*16+q):
//   0..2 = W1c[513..515]; 3 = sW2 (i<4); 4..6 = tW2 cols (i>=4); 7 = W1c[512]
//   NMEH[p] = sum_k nme[k]*W1c[384+k][j]
__global__ __launch_bounds__(256) void k_prep(const float* __restrict__ nme,
                                              const float* __restrict__ sW1,
                                              const float* __restrict__ tW1,
                                              const float* __restrict__ sW2,
                                              const float* __restrict__ tW2,
                                              u16* __restrict__ wfrag,
                                              float* __restrict__ ct,
                                              float* __restrict__ nmeh) {
  int b = blockIdx.x;
  if (b < 256) {
    int idx = b * 256 + threadIdx.x;  // 65536 total
    int j = idx & 7, l = (idx >> 3) & 63, fn = (idx >> 9) & 7, c = idx >> 12;
    int col = fn * 16 + (l & 15);
    int k = c * 32 + (l >> 4) * 8 + j;
    wfrag[idx] = f2bf(w1c(sW1, tW1, k, col));
  } else {
    int p = threadIdx.x;
    if (p >= 128) return;
    int q = p >> 3, i = p & 7, j = i * 16 + q;
    ct[0 * 128 + p] = w1c(sW1, tW1, 513, j);
    ct[1 * 128 + p] = w1c(sW1, tW1, 514, j);
    ct[2 * 128 + p] = w1c(sW1, tW1, 515, j);
    ct[3 * 128 + p] = (i < 4) ? sW2[j] : 0.f;
    if (i >= 4) {
      int jj = j - 64;
      ct[4 * 128 + p] = tW2[jj * 3 + 0];
      ct[5 * 128 + p] = tW2[jj * 3 + 1];
      ct[6 * 128 + p] = tW2[jj * 3 + 2];
    } else {
      ct[4 * 128 + p] = 0.f; ct[5 * 128 + p] = 0.f; ct[6 * 128 + p] = 0.f;
    }
    ct[7 * 128 + p] = w1c(sW1, tW1, 512, j);
    float s = 0.f;
    for (int k = 0; k < 132; ++k) s += nme[k] * w1c(sW1, tW1, 384 + k, j);
    nmeh[p] = s;
  }
}

// ---------- H_nr[65536][128] bf16 = NR_f32 x W1c[384:512], permuted store ----
// 16-row tiles, 1 wave/block, 4096 blocks -> ~16 waves/CU of TLP.
__global__ __launch_bounds__(64) void k_hnr(const float* __restrict__ nr,
                                            const u16* __restrict__ wfrag,
                                            u16* __restrict__ hnr) {
  int l = threadIdx.x, lr = l & 15, lg = l >> 4;
  int row0 = blockIdx.x * 16;
  f32x4 acc[8];
#pragma unroll
  for (int j = 0; j < 8; ++j) acc[j] = (f32x4){0.f, 0.f, 0.f, 0.f};
#pragma unroll
  for (int c2 = 0; c2 < 4; ++c2) {
    const float* ap = nr + (size_t)(row0 + lr) * 128 + c2 * 32 + lg * 8;
    bf16x8 aF = __builtin_bit_cast(bf16x8, pack8(*(const f32x4*)ap, *(const f32x4*)(ap + 4)));
    bf16x8 bF[8];
#pragma unroll
    for (int fn = 0; fn < 8; ++fn)
      bF[fn] = *(const bf16x8*)((const char*)wfrag + (size_t)((12 + c2) * 8 + fn) * 1024 + l * 16);
#pragma unroll
    for (int fn = 0; fn < 8; ++fn)
      acc[fn] = __builtin_amdgcn_mfma_f32_16x16x32_bf16(aF, bF[fn], acc[fn], 0, 0, 0);
  }
#pragma unroll
  for (int rg = 0; rg < 4; ++rg) {
    int m = row0 + lg * 4 + rg;
    uint4 pk;
    pk.x = (unsigned)f2bf(acc[0][rg]) | ((unsigned)f2bf(acc[1][rg]) << 16);
    pk.y = (unsigned)f2bf(acc[2][rg]) | ((unsigned)f2bf(acc[3][rg]) << 16);
    pk.z = (unsigned)f2bf(acc[4][rg]) | ((unsigned)f2bf(acc[5][rg]) << 16);
    pk.w = (unsigned)f2bf(acc[6][rg]) | ((unsigned)f2bf(acc[7][rg]) << 16);
    *(uint4*)(hnr + (size_t)m * 128 + lr * 8) = pk;
  }
}

// ---------- H_gf[1024][128] f32 (+b1) permuted, with STOP head fused -------
// 16-row tiles, 64 blocks x 1 wave.
__global__ __launch_bounds__(64) void k_hgf(const float* __restrict__ imr,
                                            const float* __restrict__ pgr,
                                            const float* __restrict__ nr,
                                            const int* __restrict__ focus,
                                            const u16* __restrict__ wfrag,
                                            const float* __restrict__ sb1,
                                            const float* __restrict__ tb1,
                                            const float* __restrict__ nmeh,
                                            const float* __restrict__ ct,
                                            const float* __restrict__ sb2,
                                            float* __restrict__ hgf,
                                            float* __restrict__ out0) {
  int l = threadIdx.x, lr = l & 15, lg = l >> 4;
  int row0 = blockIdx.x * 16;
  int fo = focus[row0 + lr];
  f32x4 acc[8];
#pragma unroll
  for (int j = 0; j < 8; ++j) acc[j] = (f32x4){0.f, 0.f, 0.f, 0.f};
#pragma unroll
  for (int c2 = 0; c2 < 12; ++c2) {
    const float* ap;
    if (c2 < 4)      ap = imr + (size_t)(row0 + lr) * 128 + c2 * 32;
    else if (c2 < 8) ap = pgr + (size_t)(row0 + lr) * 128 + (c2 - 4) * 32;
    else             ap = nr + (size_t)fo * 128 + (c2 - 8) * 32;
    ap += lg * 8;
    bf16x8 aF = __builtin_bit_cast(bf16x8, pack8(*(const f32x4*)ap, *(const f32x4*)(ap + 4)));
    bf16x8 bF[8];
#pragma unroll
    for (int fn = 0; fn < 8; ++fn)
      bF[fn] = *(const bf16x8*)((const char*)wfrag + (size_t)(c2 * 8 + fn) * 1024 + l * 16);
#pragma unroll
    for (int fn = 0; fn < 8; ++fn)
      acc[fn] = __builtin_amdgcn_mfma_f32_16x16x32_bf16(aF, bF[fn], acc[fn], 0, 0, 0);
  }
  f32x4 sb1v, tb1v;
#pragma unroll
  for (int fn = 0; fn < 4; ++fn) {
    sb1v[fn] = sb1[fn * 16 + lr];
    tb1v[fn] = tb1[fn * 16 + lr];
  }
  f32x4 nmv = *(const f32x4*)(nmeh + lr * 8);
  f32x4 w2v = *(const f32x4*)(ct + 3 * 128 + lr * 8);
  float sb2v = sb2[0];
#pragma unroll
  for (int rg = 0; rg < 4; ++rg) {
    int g = row0 + lg * 4 + rg;
    f32x4 v0, v1;
#pragma unroll
    for (int fn = 0; fn < 4; ++fn) v0[fn] = acc[fn][rg] + sb1v[fn];
#pragma unroll
    for (int fn = 0; fn < 4; ++fn) v1[fn] = acc[fn + 4][rg] + tb1v[fn];
    *(f32x4*)(hgf + (size_t)g * 128 + lr * 8) = v0;
    *(f32x4*)(hgf + (size_t)g * 128 + lr * 8 + 4) = v1;
    float sp = 0.f;
#pragma unroll
    for (int i = 0; i < 4; ++i) sp += fmaxf(v0[i] + nmv[i], 0.f) * w2v[i];
#pragma unroll
    for (int m = 1; m < 16; m <<= 1) sp += __shfl_xor(sp, m, 64);
    if (lr == 0) out0[E_CNT + g] = sp + sb2v;
  }
}

// ---------- hot kernel: per-edge gather + elementwise + dual head ----------
// 16 lanes/edge, lane q owns permuted units p=q*8..+7 (cols j=i*16+q: i<4
// scorer, i>=4 type). 64 edges/block (16 slices x 2 edges x 2 iterations) to
// amortize the per-lane weight loads. Dist folded as a 4th feature FMA
// (fd = dtab[d], weight row W512 in regs) -- no D10 table, -512B/edge traffic.
__global__ __launch_bounds__(256) void k_edge(
    const u16* __restrict__ hnr, const float* __restrict__ hgf,
    const float* __restrict__ ct, const int* __restrict__ tgt,
    const int* __restrict__ n2g, const float4* __restrict__ feats,
    const float* __restrict__ dtab, const float* __restrict__ sb2,
    const float* __restrict__ tb2, float* __restrict__ out0,
    float* __restrict__ out1) {
  int tid = threadIdx.x;
  int q = tid & 15;
  int base = blockIdx.x * 64 + (tid >> 4);

  // per-lane weights (loaded once per block)
  f32x4 wf1a = *(const f32x4*)(ct + 0 * 128 + q * 8), wf1b = *(const f32x4*)(ct + 0 * 128 + q * 8 + 4);
  f32x4 wf2a = *(const f32x4*)(ct + 1 * 128 + q * 8), wf2b = *(const f32x4*)(ct + 1 * 128 + q * 8 + 4);
  f32x4 wf3a = *(const f32x4*)(ct + 2 * 128 + q * 8), wf3b = *(const f32x4*)(ct + 2 * 128 + q * 8 + 4);
  f32x4 w2v  = *(const f32x4*)(ct + 3 * 128 + q * 8);
  f32x4 tw0v = *(const f32x4*)(ct + 4 * 128 + q * 8 + 4);
  f32x4 tw1v = *(const f32x4*)(ct + 5 * 128 + q * 8 + 4);
  f32x4 tw2v = *(const f32x4*)(ct + 6 * 128 + q * 8 + 4);
  f32x4 w5a  = *(const f32x4*)(ct + 7 * 128 + q * 8), w5b = *(const f32x4*)(ct + 7 * 128 + q * 8 + 4);
  float sb2v = sb2[0], tb0 = tb2[0], tb1 = tb2[1], tb2s = tb2[2];

#pragma unroll
  for (int it = 0; it < 2; ++it) {
    int eA = base + it * 32, eB = eA + 16;

    int tA = tgt[eA], tB = tgt[eB];
    int gA = n2g[tA], gB = n2g[tB];
    float4 fA = feats[eA], fB = feats[eB];
    union { uint4 v; u16 s[8]; } hnA, hnB;
    hnA.v = *(const uint4*)(hnr + (size_t)tA * 128 + q * 8);
    hnB.v = *(const uint4*)(hnr + (size_t)tB * 128 + q * 8);
    f32x4 hgA0 = *(const f32x4*)(hgf + (size_t)gA * 128 + q * 8);
    f32x4 hgA1 = *(const f32x4*)(hgf + (size_t)gA * 128 + q * 8 + 4);
    f32x4 hgB0 = *(const f32x4*)(hgf + (size_t)gB * 128 + q * 8);
    f32x4 hgB1 = *(const f32x4*)(hgf + (size_t)gB * 128 + q * 8 + 4);
    float fdA = dtab[(int)fminf(fA.x, 9.f)];
    float fdB = dtab[(int)fminf(fB.x, 9.f)];

    float scA = 0.f, t0A = 0.f, t1A = 0.f, t2A = 0.f;
#pragma unroll
    for (int i = 0; i < 4; ++i) {
      float h = hgA0[i] + b2f(hnA.s[i]) + fdA * w5a[i] + fA.y * wf1a[i] + fA.z * wf2a[i] + fA.w * wf3a[i];
      scA += fmaxf(h, 0.f) * w2v[i];
    }
#pragma unroll
    for (int i = 0; i < 4; ++i) {
      float h = hgA1[i] + b2f(hnA.s[4 + i]) + fdA * w5b[i] + fA.y * wf1b[i] + fA.z * wf2b[i] + fA.w * wf3b[i];
      float r = fmaxf(h, 0.f);
      t0A += r * tw0v[i]; t1A += r * tw1v[i]; t2A += r * tw2v[i];
    }
    float scB = 0.f, t0B = 0.f, t1B = 0.f, t2B = 0.f;
#pragma unroll
    for (int i = 0; i < 4; ++i) {
      float h = hgB0[i] + b2f(hnB.s[i]) + fdB * w5a[i] + fB.y * wf1a[i] + fB.z * wf2a[i] + fB.w * wf3a[i];
      scB += fmaxf(h, 0.f) * w2v[i];
    }
#pragma unroll
    for (int i = 0; i < 4; ++i) {
      float h = hgB1[i] + b2f(hnB.s[4 + i]) + fdB * w5b[i] + fB.y * wf1b[i] + fB.z * wf2b[i] + fB.w * wf3b[i];
      float r = fmaxf(h, 0.f);
      t0B += r * tw0v[i]; t1B += r * tw1v[i]; t2B += r * tw2v[i];
    }

#pragma unroll
    for (int m = 1; m < 16; m <<= 1) {
      scA += __shfl_xor(scA, m, 64); t0A += __shfl_xor(t0A, m, 64);
      t1A += __shfl_xor(t1A, m, 64); t2A += __shfl_xor(t2A, m, 64);
      scB += __shfl_xor(scB, m, 64); t0B += __shfl_xor(t0B, m, 64);
      t1B += __shfl_xor(t1B, m, 64); t2B += __shfl_xor(t2B, m, 64);
    }
    if (q == 0) {
      out0[eA] = scA + sb2v;
      out0[eB] = scB + sb2v;
      float* oA = out1 + (size_t)eA * 3;
      oA[0] = t0A + tb0; oA[1] = t1A + tb1; oA[2] = t2A + tb2s;
      float* oB = out1 + (size_t)eB * 3;
      oB[0] = t0B + tb0; oB[1] = t1B + tb1; oB[2] = t2B + tb2s;
    }
  }
}

extern "C" void kernel_launch(void* const* d_in, const int* in_sizes, int n_in,
                              void* d_out, int out_size, void* d_ws, size_t ws_size,
                              hipStream_t stream) {
  const float* imr   = (const float*)d_in[0];
  const float* pgr   = (const float*)d_in[1];
  const float* nr    = (const float*)d_in[2];
  const int*   focus = (const int*)d_in[3];
  const int*   n2g   = (const int*)d_in[4];
  const int*   tgt   = (const int*)d_in[5];
  const float* feats = (const float*)d_in[6];
  const float* dtab  = (const float*)d_in[8];
  const float* nme   = (const float*)d_in[9];
  const float* sW1   = (const float*)d_in[10];
  const float* sb1   = (const float*)d_in[11];
  const float* sW2   = (const float*)d_in[12];
  const float* sb2   = (const float*)d_in[13];
  const float* tW1   = (const float*)d_in[14];
  const float* tb1   = (const float*)d_in[15];
  const float* tW2   = (const float*)d_in[16];
  const float* tb2   = (const float*)d_in[17];

  char* ws = (char*)d_ws;
  u16*   HNR   = (u16*)(ws + WS_HNR);
  float* HGF   = (float*)(ws + WS_HGF);
  u16*   WFRAG = (u16*)(ws + WS_WFRAG);
  float* CT    = (float*)(ws + WS_CT);
  float* NMEH  = (float*)(ws + WS_NMEH);

  float* out0 = (float*)d_out;            // [401024]
  float* out1 = out0 + (E_CNT + G_CNT);   // [400000*3]

  k_prep<<<257, 256, 0, stream>>>(nme, sW1, tW1, sW2, tW2, WFRAG, CT, NMEH);
  k_hnr<<<4096, 64, 0, stream>>>(nr, WFRAG, HNR);
  k_hgf<<<64, 64, 0, stream>>>(imr, pgr, nr, focus, WFRAG, sb1, tb1, NMEH, CT, sb2, HGF, out0);
  k_edge<<<6250, 256, 0, stream>>>(HNR, HGF, CT, tgt, n2g, (const float4*)feats,
                                   dtab, sb2, tb2, out0, out1);
}

// Round 9
// 61.652 us; speedup vs baseline: 1.6581x; 1.0717x over previous
//
#include <hip/hip_runtime.h>

using u16    = unsigned short;
using f32x4  = __attribute__((ext_vector_type(4))) float;
using bf16x8 = __attribute__((ext_vector_type(8))) __bf16;

#define E_CNT 400000
#define G_CNT 1024

// ws layout (bytes)
#define WS_HND   0u          // H_node [65536][128] bf16 (permuted) = 16777216
#define WS_HGF   16777216u   // [1024][128] f32  (permuted, +b1)    =   524288
#define WS_WFRAG 17301504u   // [16][8][64] x 16B bf16 W1c frags    =   131072
#define WS_CT    17432576u   // [8][128] f32 (permuted)             =     4096
#define WS_NMEH  17436672u   // [128] f32 (permuted)                =      512

__device__ __forceinline__ u16 f2bf(float f) {
  unsigned u = __builtin_bit_cast(unsigned, f);
  return (u16)((u + 0x7fffu + ((u >> 16) & 1u)) >> 16);  // RNE
}
__device__ __forceinline__ float b2f(u16 v) {
  unsigned u = ((unsigned)v) << 16;
  return __builtin_bit_cast(float, u);
}
__device__ __forceinline__ uint4 pack8(f32x4 a, f32x4 b) {
  uint4 r;
  r.x = (unsigned)f2bf(a[0]) | ((unsigned)f2bf(a[1]) << 16);
  r.y = (unsigned)f2bf(a[2]) | ((unsigned)f2bf(a[3]) << 16);
  r.z = (unsigned)f2bf(b[0]) | ((unsigned)f2bf(b[1]) << 16);
  r.w = (unsigned)f2bf(b[2]) | ((unsigned)f2bf(b[3]) << 16);
  return r;
}
__device__ __forceinline__ float w1c(const float* sW1, const float* tW1, int k, int j) {
  return (j < 64) ? sW1[(size_t)k * 64 + j] : tW1[(size_t)k * 64 + (j - 64)];
}
// 16-lane sum via DPP (VALU pipe only; no LDS). quad xor1, xor2, then
// half-mirror (combines quads in 8-group), mirror (combines 8-groups in row16).
__device__ __forceinline__ float dpp_red16(float x) {
  int v;
  v = __builtin_amdgcn_update_dpp(0, __builtin_bit_cast(int, x), 0xB1, 0xF, 0xF, false);
  x += __builtin_bit_cast(float, v);
  v = __builtin_amdgcn_update_dpp(0, __builtin_bit_cast(int, x), 0x4E, 0xF, 0xF, false);
  x += __builtin_bit_cast(float, v);
  v = __builtin_amdgcn_update_dpp(0, __builtin_bit_cast(int, x), 0x141, 0xF, 0xF, false);
  x += __builtin_bit_cast(float, v);
  v = __builtin_amdgcn_update_dpp(0, __builtin_bit_cast(int, x), 0x140, 0xF, 0xF, false);
  x += __builtin_bit_cast(float, v);
  return x;
}

// ---------- precompute: WFRAG + permuted small tables ----------
__global__ __launch_bounds__(256) void k_prep(const float* __restrict__ nme,
                                              const float* __restrict__ sW1,
                                              const float* __restrict__ tW1,
                                              const float* __restrict__ sW2,
                                              const float* __restrict__ tW2,
                                              u16* __restrict__ wfrag,
                                              float* __restrict__ ct,
                                              float* __restrict__ nmeh) {
  int b = blockIdx.x;
  if (b < 256) {
    int idx = b * 256 + threadIdx.x;  // 65536 total
    int j = idx & 7, l = (idx >> 3) & 63, fn = (idx >> 9) & 7, c = idx >> 12;
    int col = fn * 16 + (l & 15);
    int k = c * 32 + (l >> 4) * 8 + j;
    wfrag[idx] = f2bf(w1c(sW1, tW1, k, col));
  } else {
    int p = threadIdx.x;
    if (p >= 128) return;
    int q = p >> 3, i = p & 7, j = i * 16 + q;
    ct[0 * 128 + p] = w1c(sW1, tW1, 513, j);
    ct[1 * 128 + p] = w1c(sW1, tW1, 514, j);
    ct[2 * 128 + p] = w1c(sW1, tW1, 515, j);
    ct[3 * 128 + p] = (i < 4) ? sW2[j] : 0.f;
    if (i >= 4) {
      int jj = j - 64;
      ct[4 * 128 + p] = tW2[jj * 3 + 0];
      ct[5 * 128 + p] = tW2[jj * 3 + 1];
      ct[6 * 128 + p] = tW2[jj * 3 + 2];
    } else {
      ct[4 * 128 + p] = 0.f; ct[5 * 128 + p] = 0.f; ct[6 * 128 + p] = 0.f;
    }
    ct[7 * 128 + p] = w1c(sW1, tW1, 512, j);
    float s = 0.f;
    for (int k = 0; k < 132; ++k) s += nme[k] * w1c(sW1, tW1, 384 + k, j);
    nmeh[p] = s;
  }
}

// ---------- H_gf[1024][128] f32 (+b1) permuted, with STOP head fused -------
__global__ __launch_bounds__(64) void k_hgf(const float* __restrict__ imr,
                                            const float* __restrict__ pgr,
                                            const float* __restrict__ nr,
                                            const int* __restrict__ focus,
                                            const u16* __restrict__ wfrag,
                                            const float* __restrict__ sb1,
                                            const float* __restrict__ tb1,
                                            const float* __restrict__ nmeh,
                                            const float* __restrict__ ct,
                                            const float* __restrict__ sb2,
                                            float* __restrict__ hgf,
                                            float* __restrict__ out0) {
  int l = threadIdx.x, lr = l & 15, lg = l >> 4;
  int row0 = blockIdx.x * 16;
  int fo = focus[row0 + lr];
  f32x4 acc[8];
#pragma unroll
  for (int j = 0; j < 8; ++j) acc[j] = (f32x4){0.f, 0.f, 0.f, 0.f};
#pragma unroll
  for (int c2 = 0; c2 < 12; ++c2) {
    const float* ap;
    if (c2 < 4)      ap = imr + (size_t)(row0 + lr) * 128 + c2 * 32;
    else if (c2 < 8) ap = pgr + (size_t)(row0 + lr) * 128 + (c2 - 4) * 32;
    else             ap = nr + (size_t)fo * 128 + (c2 - 8) * 32;
    ap += lg * 8;
    bf16x8 aF = __builtin_bit_cast(bf16x8, pack8(*(const f32x4*)ap, *(const f32x4*)(ap + 4)));
    bf16x8 bF[8];
#pragma unroll
    for (int fn = 0; fn < 8; ++fn)
      bF[fn] = *(const bf16x8*)((const char*)wfrag + (size_t)(c2 * 8 + fn) * 1024 + l * 16);
#pragma unroll
    for (int fn = 0; fn < 8; ++fn)
      acc[fn] = __builtin_amdgcn_mfma_f32_16x16x32_bf16(aF, bF[fn], acc[fn], 0, 0, 0);
  }
  f32x4 sb1v, tb1v;
#pragma unroll
  for (int fn = 0; fn < 4; ++fn) {
    sb1v[fn] = sb1[fn * 16 + lr];
    tb1v[fn] = tb1[fn * 16 + lr];
  }
  f32x4 nmv = *(const f32x4*)(nmeh + lr * 8);
  f32x4 w2v = *(const f32x4*)(ct + 3 * 128 + lr * 8);
  float sb2v = sb2[0];
#pragma unroll
  for (int rg = 0; rg < 4; ++rg) {
    int g = row0 + lg * 4 + rg;
    f32x4 v0, v1;
#pragma unroll
    for (int fn = 0; fn < 4; ++fn) v0[fn] = acc[fn][rg] + sb1v[fn];
#pragma unroll
    for (int fn = 0; fn < 4; ++fn) v1[fn] = acc[fn + 4][rg] + tb1v[fn];
    *(f32x4*)(hgf + (size_t)g * 128 + lr * 8) = v0;
    *(f32x4*)(hgf + (size_t)g * 128 + lr * 8 + 4) = v1;
    float sp = 0.f;
#pragma unroll
    for (int i = 0; i < 4; ++i) sp += fmaxf(v0[i] + nmv[i], 0.f) * w2v[i];
#pragma unroll
    for (int m = 1; m < 16; m <<= 1) sp += __shfl_xor(sp, m, 64);
    if (lr == 0) out0[E_CNT + g] = sp + sb2v;
  }
}

// ---------- H_node[t] = NR[t] x W1c[384:512]  +  HGF[n2g[t]]  (bf16) -------
// One gather per edge later instead of two: the n2g chase is folded here,
// where it's a coalesced per-node read (n2g sorted -> L1-hot HGF rows).
__global__ __launch_bounds__(64) void k_hnode(const float* __restrict__ nr,
                                              const u16* __restrict__ wfrag,
                                              const int* __restrict__ n2g,
                                              const float* __restrict__ hgf,
                                              u16* __restrict__ hnode) {
  int l = threadIdx.x, lr = l & 15, lg = l >> 4;
  int row0 = blockIdx.x * 16;
  f32x4 acc[8];
#pragma unroll
  for (int j = 0; j < 8; ++j) acc[j] = (f32x4){0.f, 0.f, 0.f, 0.f};
#pragma unroll
  for (int c2 = 0; c2 < 4; ++c2) {
    const float* ap = nr + (size_t)(row0 + lr) * 128 + c2 * 32 + lg * 8;
    bf16x8 aF = __builtin_bit_cast(bf16x8, pack8(*(const f32x4*)ap, *(const f32x4*)(ap + 4)));
    bf16x8 bF[8];
#pragma unroll
    for (int fn = 0; fn < 8; ++fn)
      bF[fn] = *(const bf16x8*)((const char*)wfrag + (size_t)((12 + c2) * 8 + fn) * 1024 + l * 16);
#pragma unroll
    for (int fn = 0; fn < 8; ++fn)
      acc[fn] = __builtin_amdgcn_mfma_f32_16x16x32_bf16(aF, bF[fn], acc[fn], 0, 0, 0);
  }
#pragma unroll
  for (int rg = 0; rg < 4; ++rg) {
    int m = row0 + lg * 4 + rg;
    int g = n2g[m];
    f32x4 v0 = *(const f32x4*)(hgf + (size_t)g * 128 + lr * 8);
    f32x4 v1 = *(const f32x4*)(hgf + (size_t)g * 128 + lr * 8 + 4);
    f32x4 s0, s1;
#pragma unroll
    for (int i = 0; i < 4; ++i) { s0[i] = acc[i][rg] + v0[i]; s1[i] = acc[i + 4][rg] + v1[i]; }
    *(uint4*)(hnode + (size_t)m * 128 + lr * 8) = pack8(s0, s1);
  }
}

// ---------- hot kernel: ONE gather per edge + elementwise + dual head ------
// 16 lanes/edge, lane q owns permuted units p=q*8..+7. 4 consecutive edges
// per slice (all loads issued up front = 4 independent chains), DPP
// reductions (no LDS pipe), float4-coalesced stores.
__global__ __launch_bounds__(256) void k_edge(
    const u16* __restrict__ hnode, const float* __restrict__ ct,
    const int* __restrict__ tgt, const float4* __restrict__ feats,
    const float* __restrict__ dtab, const float* __restrict__ sb2,
    const float* __restrict__ tb2, float* __restrict__ out0,
    float* __restrict__ out1) {
  int tid = threadIdx.x;
  int q = tid & 15;
  int e0 = blockIdx.x * 64 + (tid >> 4) * 4;

  f32x4 wf1a = *(const f32x4*)(ct + 0 * 128 + q * 8), wf1b = *(const f32x4*)(ct + 0 * 128 + q * 8 + 4);
  f32x4 wf2a = *(const f32x4*)(ct + 1 * 128 + q * 8), wf2b = *(const f32x4*)(ct + 1 * 128 + q * 8 + 4);
  f32x4 wf3a = *(const f32x4*)(ct + 2 * 128 + q * 8), wf3b = *(const f32x4*)(ct + 2 * 128 + q * 8 + 4);
  f32x4 w2v  = *(const f32x4*)(ct + 3 * 128 + q * 8);
  f32x4 tw0v = *(const f32x4*)(ct + 4 * 128 + q * 8 + 4);
  f32x4 tw1v = *(const f32x4*)(ct + 5 * 128 + q * 8 + 4);
  f32x4 tw2v = *(const f32x4*)(ct + 6 * 128 + q * 8 + 4);
  f32x4 w5a  = *(const f32x4*)(ct + 7 * 128 + q * 8), w5b = *(const f32x4*)(ct + 7 * 128 + q * 8 + 4);
  float sb2v = sb2[0], tb0 = tb2[0], tb1 = tb2[1], tb2s = tb2[2];

  int t[4];
#pragma unroll
  for (int j = 0; j < 4; ++j) t[j] = tgt[e0 + j];
  float4 f[4];
#pragma unroll
  for (int j = 0; j < 4; ++j) f[j] = feats[e0 + j];
  union { uint4 v; u16 s[8]; } hn[4];
#pragma unroll
  for (int j = 0; j < 4; ++j)
    hn[j].v = *(const uint4*)(hnode + (size_t)t[j] * 128 + q * 8);
  float fd[4];
#pragma unroll
  for (int j = 0; j < 4; ++j) fd[j] = dtab[(int)fminf(f[j].x, 9.f)];

  float sc[4], t0[4], t1[4], t2[4];
#pragma unroll
  for (int j = 0; j < 4; ++j) {
    float s = 0.f, a0 = 0.f, a1 = 0.f, a2 = 0.f;
#pragma unroll
    for (int i = 0; i < 4; ++i) {
      float h = b2f(hn[j].s[i]) + fd[j] * w5a[i] + f[j].y * wf1a[i] + f[j].z * wf2a[i] + f[j].w * wf3a[i];
      s += fmaxf(h, 0.f) * w2v[i];
    }
#pragma unroll
    for (int i = 0; i < 4; ++i) {
      float h = b2f(hn[j].s[4 + i]) + fd[j] * w5b[i] + f[j].y * wf1b[i] + f[j].z * wf2b[i] + f[j].w * wf3b[i];
      float r = fmaxf(h, 0.f);
      a0 += r * tw0v[i]; a1 += r * tw1v[i]; a2 += r * tw2v[i];
    }
    sc[j] = s; t0[j] = a0; t1[j] = a1; t2[j] = a2;
  }
#pragma unroll
  for (int j = 0; j < 4; ++j) {
    sc[j] = dpp_red16(sc[j]); t0[j] = dpp_red16(t0[j]);
    t1[j] = dpp_red16(t1[j]); t2[j] = dpp_red16(t2[j]);
  }
  if (q == 0) {
    *(float4*)(out0 + e0) = make_float4(sc[0] + sb2v, sc[1] + sb2v, sc[2] + sb2v, sc[3] + sb2v);
    float* o = out1 + (size_t)e0 * 3;  // 12 consecutive f32, 16B-aligned
    *(float4*)(o + 0) = make_float4(t0[0] + tb0, t1[0] + tb1, t2[0] + tb2s, t0[1] + tb0);
    *(float4*)(o + 4) = make_float4(t1[1] + tb1, t2[1] + tb2s, t0[2] + tb0, t1[2] + tb1);
    *(float4*)(o + 8) = make_float4(t2[2] + tb2s, t0[3] + tb0, t1[3] + tb1, t2[3] + tb2s);
  }
}

extern "C" void kernel_launch(void* const* d_in, const int* in_sizes, int n_in,
                              void* d_out, int out_size, void* d_ws, size_t ws_size,
                              hipStream_t stream) {
  const float* imr   = (const float*)d_in[0];
  const float* pgr   = (const float*)d_in[1];
  const float* nr    = (const float*)d_in[2];
  const int*   focus = (const int*)d_in[3];
  const int*   n2g   = (const int*)d_in[4];
  const int*   tgt   = (const int*)d_in[5];
  const float* feats = (const float*)d_in[6];
  const float* dtab  = (const float*)d_in[8];
  const float* nme   = (const float*)d_in[9];
  const float* sW1   = (const float*)d_in[10];
  const float* sb1   = (const float*)d_in[11];
  const float* sW2   = (const float*)d_in[12];
  const float* sb2   = (const float*)d_in[13];
  const float* tW1   = (const float*)d_in[14];
  const float* tb1   = (const float*)d_in[15];
  const float* tW2   = (const float*)d_in[16];
  const float* tb2   = (const float*)d_in[17];

  char* ws = (char*)d_ws;
  u16*   HND   = (u16*)(ws + WS_HND);
  float* HGF   = (float*)(ws + WS_HGF);
  u16*   WFRAG = (u16*)(ws + WS_WFRAG);
  float* CT    = (float*)(ws + WS_CT);
  float* NMEH  = (float*)(ws + WS_NMEH);

  float* out0 = (float*)d_out;            // [401024]
  float* out1 = out0 + (E_CNT + G_CNT);   // [400000*3]

  k_prep<<<257, 256, 0, stream>>>(nme, sW1, tW1, sW2, tW2, WFRAG, CT, NMEH);
  k_hgf<<<64, 64, 0, stream>>>(imr, pgr, nr, focus, WFRAG, sb1, tb1, NMEH, CT, sb2, HGF, out0);
  k_hnode<<<4096, 64, 0, stream>>>(nr, WFRAG, n2g, HGF, HND);
  k_edge<<<6250, 256, 0, stream>>>(HND, CT, tgt, (const float4*)feats,
                                   dtab, sb2, tb2, out0, out1);
}